// Round 1
// baseline (101.783 us; speedup 1.0000x reference)
//
#include <hip/hip_runtime.h>
#include <math.h>

// Problem constants (from reference: N=512, D=4096, fp32).
#define PN 512
#define PD 4096

// Fused single-pass-K GEMM config: 32x32 C-tile, K staged in BK chunks.
#define BK 256
#define NST (PD / BK)  // 16 stages

// ws layout (bytes):
//   [0,2048)    sa (512 f32)        float idx 0
//   [2048,4096) sp                  float idx 512
//   [4096,6144) dd (diag dist)      float idx 1024
//   [6144]      sum (f32 atomic)    float idx 1536
//   [6148]      cnt (u32 atomic)    idx 1537
//   [6152]      done (u32 ticket)   idx 1538
//   [8192, +4MB)        ah bf16 [512][4096]
//   [8192+4MB, +8MB)    ph bf16 [512][4096]
#define WS_AH_BYTES 8192
#define WS_PH_BYTES (8192 + 4194304)
#define WS_NEED_MAIN ((size_t)(8192 + 2 * 4194304))

typedef __attribute__((ext_vector_type(8))) short short8;
typedef __attribute__((ext_vector_type(4))) float floatx4;

static __device__ __forceinline__ unsigned short f2bf(float x) {
    // round-to-nearest-even fp32 -> bf16 (inputs are finite normals)
    unsigned int u = __float_as_uint(x);
    u += 0x7fffu + ((u >> 16) & 1u);
    return (unsigned short)(u >> 16);
}

static __device__ __forceinline__ void load16_lds(const void* gp, void* lp) {
    // 16B per lane, LDS dest = wave-uniform base + lane*16
    __builtin_amdgcn_global_load_lds(
        (const __attribute__((address_space(1))) unsigned int*)gp,
        (__attribute__((address_space(3))) unsigned int*)lp,
        16, 0, 0);
}

struct ushort4s { unsigned short x, y, z, w; };

// ---------------- prep: norms + diag dist + fp32->bf16 conversion ----------------
__global__ __launch_bounds__(256) void taw_prep_kernel(
        const float* __restrict__ a, const float* __restrict__ p,
        float* __restrict__ ws, int conv) {
    const int i = blockIdx.x;
    const int t = threadIdx.x;
    if (i == 0 && t == 0) {
        ws[1536] = 0.0f;
        ((unsigned int*)ws)[1537] = 0u;
        ((unsigned int*)ws)[1538] = 0u;
    }
    const float4* a4 = (const float4*)(a + (size_t)i * PD);
    const float4* p4 = (const float4*)(p + (size_t)i * PD);
    unsigned short* ah = (unsigned short*)((char*)ws + WS_AH_BYTES) + (size_t)i * PD;
    unsigned short* ph = (unsigned short*)((char*)ws + WS_PH_BYTES) + (size_t)i * PD;
    float sa = 0.f, sp = 0.f, dp = 0.f;
#pragma unroll
    for (int c = 0; c < 4; ++c) {
        const int e = c * 256 + t;      // float4 index
        float4 av = a4[e];
        float4 pv = p4[e];
        sa += av.x * av.x + av.y * av.y + av.z * av.z + av.w * av.w;
        sp += pv.x * pv.x + pv.y * pv.y + pv.z * pv.z + pv.w * pv.w;
        dp += av.x * pv.x + av.y * pv.y + av.z * pv.z + av.w * pv.w;
        if (conv) {
            ushort4s ab = {f2bf(av.x), f2bf(av.y), f2bf(av.z), f2bf(av.w)};
            ushort4s pb = {f2bf(pv.x), f2bf(pv.y), f2bf(pv.z), f2bf(pv.w)};
            *(ushort4s*)(ah + (size_t)e * 4) = ab;
            *(ushort4s*)(ph + (size_t)e * 4) = pb;
        }
    }
#pragma unroll
    for (int off = 32; off > 0; off >>= 1) {
        sa += __shfl_down(sa, off, 64);
        sp += __shfl_down(sp, off, 64);
        dp += __shfl_down(dp, off, 64);
    }
    __shared__ float red[3][4];
    const int wave = t >> 6;
    if ((t & 63) == 0) { red[0][wave] = sa; red[1][wave] = sp; red[2][wave] = dp; }
    __syncthreads();
    if (t == 0) {
        sa = red[0][0] + red[0][1] + red[0][2] + red[0][3];
        sp = red[1][0] + red[1][1] + red[1][2] + red[1][3];
        dp = red[2][0] + red[2][1] + red[2][2] + red[2][3];
        float d2 = sa - 2.f * dp + sp;
        d2 = fmaxf(d2, 0.f);
        ws[i] = sa;
        ws[512 + i] = sp;
        ws[1024 + i] = (d2 == 0.f) ? 0.f : sqrtf(d2);
    }
}

// ---------------- fused single-pass GEMM + epilogue + finalize ----------------
// grid 256 blocks (XCD-chunked swizzle over the 16x16 tile grid), 256 threads =
// 4 waves; wave w owns the 16x16 quadrant (w>>1, w&1) of a 32x32 C-tile.
// LDS in MFMA fragment order: lds[buf][32 groups][64 lanes][8 bf16].
// Group g (per tensor, g=kb*2+rh): lane l holds row rh*16+(l&15),
// k = kb*32 + (l>>4)*8 of the current BK=256 K-slab. A = groups 0..15,
// P = groups 16..31.
__global__ __launch_bounds__(256) void taw_fused_kernel(
        float* __restrict__ ws, float* __restrict__ out) {
    __shared__ short lds[2][32][64][8];  // 64 KB double buffer
    const unsigned short* ah = (const unsigned short*)((const char*)ws + WS_AH_BYTES);
    const unsigned short* ph = (const unsigned short*)((const char*)ws + WS_PH_BYTES);
    const int t = threadIdx.x;
    const int lane = t & 63;
    const int w = t >> 6;
    const int wm = w >> 1, wn = w & 1;

    // XCD-chunked swizzle: hardware maps linear block B to XCD B&7 (heuristic).
    // Give each XCD a 4x8 chunk of the 16x16 tile grid -> working set
    // (128 A-rows + 256 P-rows = 3.1 MB bf16) fits its 4 MB L2.
    const int B = blockIdx.x;
    const int xcd = B & 7;
    const int l = B >> 3;                 // 0..31 within XCD
    const int bi = ((xcd >> 1) << 2) + (l >> 3);   // 0..15
    const int bj = ((xcd & 1) << 3) + (l & 7);     // 0..15
    const int i0 = bi * 32;
    const int j0 = bj * 32;

    // Per-thread staging base addresses (8 global_load_lds per stage; wave w
    // stages groups g16 = w*8+q). All q compile-time via unroll.
    const unsigned short* sbase[8];
#pragma unroll
    for (int q = 0; q < 8; ++q) {
        const int g16 = w * 8 + q;
        const int g = g16 & 15;
        const int row = ((g & 1) << 4) + (lane & 15);
        const int kk = ((g >> 1) << 5) + ((lane >> 4) << 3);
        sbase[q] = (g16 < 16 ? ah + (size_t)(i0 + row) * PD
                             : ph + (size_t)(j0 + row) * PD) + kk;
    }

    auto STAGE = [&](int buf, int kst) {
#pragma unroll
        for (int q = 0; q < 8; ++q) {
            load16_lds(sbase[q] + kst, &lds[buf][w * 8 + q][0][0]);
        }
    };

    floatx4 acc[4];
#pragma unroll
    for (int c = 0; c < 4; ++c) acc[c] = (floatx4){0.f, 0.f, 0.f, 0.f};

    STAGE(0, 0);
    __syncthreads();  // drains vmcnt(0): buf0 staged
    for (int st = 0; st < NST; ++st) {
        if (st + 1 < NST) STAGE((st + 1) & 1, (st + 1) * BK);
        const int b = st & 1;
#pragma unroll
        for (int kb = 0; kb < 8; ++kb) {
            short8 af = *(const short8*)&lds[b][kb * 2 + wm][lane][0];
            short8 bf = *(const short8*)&lds[b][16 + kb * 2 + wn][lane][0];
            acc[kb & 3] = __builtin_amdgcn_mfma_f32_16x16x32_bf16(af, bf, acc[kb & 3], 0, 0, 0);
        }
        __syncthreads();  // drains vmcnt(0) (next buf staged) + all ds_reads of buf b
    }

    const floatx4 dot = acc[0] + acc[1] + acc[2] + acc[3];

    // Epilogue: C/D layout col=lane&15, row=(lane>>4)*4+r [m89-verified]
    const int jj = j0 + wn * 16 + (lane & 15);
    const int ib = i0 + wm * 16 + ((lane >> 4) << 2);
    const float sp = ws[512 + jj];
    float lsum = 0.f;
    unsigned int lcnt = 0;
#pragma unroll
    for (int r = 0; r < 4; ++r) {
        const int ii = ib + r;
        float d2 = ws[ii] - 2.f * dot[r] + sp;
        d2 = fmaxf(d2, 0.f);
        const float dist = (d2 == 0.f) ? 0.f : sqrtf(d2);
        const float v = (ii != jj) ? fmaxf(ws[1024 + ii] - dist, 0.f) : 0.f;
        lsum += v;
        lcnt += (v > 1e-16f) ? 1u : 0u;
    }
#pragma unroll
    for (int off = 32; off > 0; off >>= 1) {
        lsum += __shfl_down(lsum, off, 64);
        lcnt += __shfl_down(lcnt, off, 64);
    }
    __shared__ float rsum[4];
    __shared__ unsigned int rcnt[4];
    if ((t & 63) == 0) { rsum[w] = lsum; rcnt[w] = lcnt; }
    __syncthreads();
    if (t == 0) {
        atomicAdd(ws + 1536, rsum[0] + rsum[1] + rsum[2] + rsum[3]);
        atomicAdd(((unsigned int*)ws) + 1537, rcnt[0] + rcnt[1] + rcnt[2] + rcnt[3]);
        __threadfence();  // make this block's sums device-visible before ticket
        const unsigned int old = atomicAdd(((unsigned int*)ws) + 1538, 1u);
        if (old == 255u) {  // last block: all 256 blocks' atomics are visible
            const float s = atomicAdd(ws + 1536, 0.f);          // coherent read
            const unsigned int c = atomicAdd(((unsigned int*)ws) + 1537, 0u);
            out[0] = (float)((double)s / ((double)c + 1e-16));
        }
    }
}

// ---------------- finalize (fallback path only) ----------------
__global__ void taw_finalize_kernel(const float* __restrict__ ws,
                                    float* __restrict__ out) {
    const double s = (double)ws[1536];
    const double c = (double)(((const unsigned int*)ws)[1537]);
    out[0] = (float)(s / (c + 1e-16));
}

// ---------------- fallback single-pass fp32 GEMM (Round-0/1 proven path) ----------------
__global__ __launch_bounds__(256) void taw_gemm_loss_kernel(
        const float* __restrict__ A, const float* __restrict__ P,
        float* __restrict__ ws) {
    __shared__ float as[32][34];
    __shared__ float bs[32][34];
    const int tx = threadIdx.x;
    const int ty = threadIdx.y;
    const int t = ty * 16 + tx;
    const int i0 = blockIdx.y * 32;
    const int j0 = blockIdx.x * 32;
    const int sr = t >> 3;
    const int sk = (t & 7) * 4;
    const float* aptr = A + (size_t)(i0 + sr) * PD + sk;
    const float* pptr = P + (size_t)(j0 + sr) * PD + sk;
    float c00 = 0.f, c01 = 0.f, c10 = 0.f, c11 = 0.f;
    for (int k0 = 0; k0 < PD; k0 += 32) {
        float4 av = *(const float4*)(aptr + k0);
        float4 pv = *(const float4*)(pptr + k0);
        __syncthreads();
        as[sk + 0][sr] = av.x; as[sk + 1][sr] = av.y;
        as[sk + 2][sr] = av.z; as[sk + 3][sr] = av.w;
        bs[sk + 0][sr] = pv.x; bs[sk + 1][sr] = pv.y;
        bs[sk + 2][sr] = pv.z; bs[sk + 3][sr] = pv.w;
        __syncthreads();
#pragma unroll
        for (int kk = 0; kk < 32; ++kk) {
            const float2 a2 = *(const float2*)&as[kk][2 * ty];
            const float2 b2 = *(const float2*)&bs[kk][2 * tx];
            c00 = fmaf(a2.x, b2.x, c00);
            c01 = fmaf(a2.x, b2.y, c01);
            c10 = fmaf(a2.y, b2.x, c10);
            c11 = fmaf(a2.y, b2.y, c11);
        }
    }
    const float* sq_a = ws;
    const float* sq_p = ws + 512;
    const float* ddg  = ws + 1024;
    const int i = i0 + 2 * ty;
    const int j = j0 + 2 * tx;
    float cvals[2][2] = {{c00, c01}, {c10, c11}};
    float lsum = 0.f;
    unsigned int lcnt = 0;
#pragma unroll
    for (int dr = 0; dr < 2; ++dr)
#pragma unroll
        for (int dc = 0; dc < 2; ++dc) {
            const int ii = i + dr, jj = j + dc;
            float d2 = sq_a[ii] - 2.f * cvals[dr][dc] + sq_p[jj];
            d2 = fmaxf(d2, 0.f);
            const float dist = (d2 == 0.f) ? 0.f : sqrtf(d2);
            const float v = (ii != jj) ? fmaxf(ddg[ii] - dist, 0.f) : 0.f;
            lsum += v;
            lcnt += (v > 1e-16f) ? 1u : 0u;
        }
#pragma unroll
    for (int off = 32; off > 0; off >>= 1) {
        lsum += __shfl_down(lsum, off, 64);
        lcnt += __shfl_down(lcnt, off, 64);
    }
    __shared__ float rsum[4];
    __shared__ unsigned int rcnt[4];
    if ((t & 63) == 0) { rsum[t >> 6] = lsum; rcnt[t >> 6] = lcnt; }
    __syncthreads();
    if (t == 0) {
        atomicAdd(ws + 1536, rsum[0] + rsum[1] + rsum[2] + rsum[3]);
        atomicAdd(((unsigned int*)ws) + 1537, rcnt[0] + rcnt[1] + rcnt[2] + rcnt[3]);
    }
}

extern "C" void kernel_launch(void* const* d_in, const int* in_sizes, int n_in,
                              void* d_out, int out_size, void* d_ws, size_t ws_size,
                              hipStream_t stream) {
    (void)in_sizes; (void)n_in; (void)out_size;
    const float* a = (const float*)d_in[0];
    const float* p = (const float*)d_in[1];
    float* out = (float*)d_out;
    float* ws = (float*)d_ws;

    const int use_mfma = (ws_size >= WS_NEED_MAIN) ? 1 : 0;
    taw_prep_kernel<<<PN, 256, 0, stream>>>(a, p, ws, use_mfma);
    if (use_mfma) {
        taw_fused_kernel<<<256, 256, 0, stream>>>(ws, out);
    } else {
        taw_gemm_loss_kernel<<<dim3(16, 16), dim3(16, 16), 0, stream>>>(a, p, ws);
        taw_finalize_kernel<<<1, 1, 0, stream>>>(ws, out);
    }
}

// Round 2
// 94.349 us; speedup vs baseline: 1.0788x; 1.0788x over previous
//
#include <hip/hip_runtime.h>
#include <math.h>

// Problem constants (from reference: N=512, D=4096, fp32).
#define PN 512
#define PD 4096

// Fused single-pass-K GEMM config: 32x32 C-tile, K staged in BK chunks,
// triple-buffered LDS with counted-vmcnt pipeline (T3/T4).
#define BK 256
#define NST (PD / BK)  // 16 stages

// ws layout (bytes):
//   [0,2048)    sa (512 f32)        float idx 0
//   [2048,4096) sp                  float idx 512
//   [4096,6144) dd (diag dist)      float idx 1024
//   [6144]      sum (f32 atomic)    float idx 1536
//   [6148]      cnt (u32 atomic)    idx 1537
//   [6152]      done (u32 ticket)   idx 1538
//   [8192, +4MB)        ah bf16 [512][4096]
//   [8192+4MB, +8MB)    ph bf16 [512][4096]
#define WS_AH_BYTES 8192
#define WS_PH_BYTES (8192 + 4194304)
#define WS_NEED_MAIN ((size_t)(8192 + 2 * 4194304))

typedef __attribute__((ext_vector_type(8))) short short8;
typedef __attribute__((ext_vector_type(4))) float floatx4;

static __device__ __forceinline__ unsigned short f2bf(float x) {
    // round-to-nearest-even fp32 -> bf16 (inputs are finite normals)
    unsigned int u = __float_as_uint(x);
    u += 0x7fffu + ((u >> 16) & 1u);
    return (unsigned short)(u >> 16);
}

static __device__ __forceinline__ void load16_lds(const void* gp, void* lp) {
    // 16B per lane, LDS dest = wave-uniform base + lane*16
    __builtin_amdgcn_global_load_lds(
        (const __attribute__((address_space(1))) unsigned int*)gp,
        (__attribute__((address_space(3))) unsigned int*)lp,
        16, 0, 0);
}

struct ushort4s { unsigned short x, y, z, w; };

// ---------------- prep: norms + diag dist + fp32->bf16 conversion ----------------
__global__ __launch_bounds__(256) void taw_prep_kernel(
        const float* __restrict__ a, const float* __restrict__ p,
        float* __restrict__ ws, int conv) {
    const int i = blockIdx.x;
    const int t = threadIdx.x;
    if (i == 0 && t == 0) {
        ws[1536] = 0.0f;
        ((unsigned int*)ws)[1537] = 0u;
        ((unsigned int*)ws)[1538] = 0u;
    }
    const float4* a4 = (const float4*)(a + (size_t)i * PD);
    const float4* p4 = (const float4*)(p + (size_t)i * PD);
    unsigned short* ah = (unsigned short*)((char*)ws + WS_AH_BYTES) + (size_t)i * PD;
    unsigned short* ph = (unsigned short*)((char*)ws + WS_PH_BYTES) + (size_t)i * PD;
    float sa = 0.f, sp = 0.f, dp = 0.f;
#pragma unroll
    for (int c = 0; c < 4; ++c) {
        const int e = c * 256 + t;      // float4 index
        float4 av = a4[e];
        float4 pv = p4[e];
        sa += av.x * av.x + av.y * av.y + av.z * av.z + av.w * av.w;
        sp += pv.x * pv.x + pv.y * pv.y + pv.z * pv.z + pv.w * pv.w;
        dp += av.x * pv.x + av.y * pv.y + av.z * pv.z + av.w * pv.w;
        if (conv) {
            ushort4s ab = {f2bf(av.x), f2bf(av.y), f2bf(av.z), f2bf(av.w)};
            ushort4s pb = {f2bf(pv.x), f2bf(pv.y), f2bf(pv.z), f2bf(pv.w)};
            *(ushort4s*)(ah + (size_t)e * 4) = ab;
            *(ushort4s*)(ph + (size_t)e * 4) = pb;
        }
    }
#pragma unroll
    for (int off = 32; off > 0; off >>= 1) {
        sa += __shfl_down(sa, off, 64);
        sp += __shfl_down(sp, off, 64);
        dp += __shfl_down(dp, off, 64);
    }
    __shared__ float red[3][4];
    const int wave = t >> 6;
    if ((t & 63) == 0) { red[0][wave] = sa; red[1][wave] = sp; red[2][wave] = dp; }
    __syncthreads();
    if (t == 0) {
        sa = red[0][0] + red[0][1] + red[0][2] + red[0][3];
        sp = red[1][0] + red[1][1] + red[1][2] + red[1][3];
        dp = red[2][0] + red[2][1] + red[2][2] + red[2][3];
        float d2 = sa - 2.f * dp + sp;
        d2 = fmaxf(d2, 0.f);
        ws[i] = sa;
        ws[512 + i] = sp;
        ws[1024 + i] = (d2 == 0.f) ? 0.f : sqrtf(d2);
    }
}

// ---------------- fused single-pass GEMM + epilogue + finalize ----------------
// grid 256 blocks (XCD-chunked swizzle over the 16x16 tile grid), 256 threads =
// 4 waves. K is split ACROSS waves: wave w computes the FULL 32x32 tile over
// k-chunks kb in {2w, 2w+1} of each BK=256 slab (2x2 fragment grid -> each
// staged LDS element is ds_read exactly once). Partial accumulators are
// reduced across waves through LDS in the epilogue.
// LDS fragment order: lds[buf][32 groups][64 lanes][8 bf16]. Group g (per
// tensor, g=kb*2+rh): lane l holds row rh*16+(l&15), k = kb*32+(l>>4)*8.
// A = groups 0..15, P = groups 16..31.
// Pipeline: triple buffer, prefetch depth 2, counted s_waitcnt vmcnt(16)
// (8 global_load_lds per wave per stage stay in flight across barriers).
__global__ __launch_bounds__(256) void taw_fused_kernel(
        float* __restrict__ ws, float* __restrict__ out) {
    __shared__ short lds[3][32][64][8];  // 96 KB triple buffer
    const unsigned short* ah = (const unsigned short*)((const char*)ws + WS_AH_BYTES);
    const unsigned short* ph = (const unsigned short*)((const char*)ws + WS_PH_BYTES);
    const int t = threadIdx.x;
    const int lane = t & 63;
    const int w = t >> 6;

    // XCD-chunked swizzle: linear block B maps to XCD B&7 (heuristic). Each
    // XCD gets a 4x8 chunk of the 16x16 tile grid -> per-XCD working set
    // (128 A-rows + 256 P-rows = 3 MB bf16) fits its 4 MB L2.
    const int B = blockIdx.x;
    const int xcd = B & 7;
    const int l = B >> 3;                 // 0..31 within XCD
    const int bi = ((xcd >> 1) << 2) + (l >> 3);   // 0..15
    const int bj = ((xcd & 1) << 3) + (l & 7);     // 0..15
    const int i0 = bi * 32;
    const int j0 = bj * 32;

    // Staging: wave w stages groups w*8..w*8+7 (8 x global_load_lds / stage).
    const unsigned short* sbase[8];
#pragma unroll
    for (int q = 0; q < 8; ++q) {
        const int g16 = w * 8 + q;
        const int g = g16 & 15;
        const int row = ((g & 1) << 4) + (lane & 15);
        const int kk = ((g >> 1) << 5) + ((lane >> 4) << 3);
        sbase[q] = (g16 < 16 ? ah + (size_t)(i0 + row) * PD
                             : ph + (size_t)(j0 + row) * PD) + kk;
    }

    auto STAGE = [&](int buf, int kst) {
#pragma unroll
        for (int q = 0; q < 8; ++q) {
            load16_lds(sbase[q] + kst, &lds[buf][w * 8 + q][0][0]);
        }
    };

    floatx4 acc[2][2];
#pragma unroll
    for (int rm = 0; rm < 2; ++rm)
#pragma unroll
        for (int rn = 0; rn < 2; ++rn) acc[rm][rn] = (floatx4){0.f, 0.f, 0.f, 0.f};

    STAGE(0, 0);
    STAGE(1, BK);
    for (int st = 0; st < NST; ++st) {
        const int b = st - (st / 3) * 3;  // st % 3
        if (st + 2 < NST) {
            STAGE(st + 2 - ((st + 2) / 3) * 3, (st + 2) * BK);
            // stage st+1, st+2 loads (16/wave) stay in flight; stage st landed
            asm volatile("s_waitcnt vmcnt(16)" ::: "memory");
        } else if (st + 1 < NST) {
            asm volatile("s_waitcnt vmcnt(8)" ::: "memory");
        } else {
            asm volatile("s_waitcnt vmcnt(0)" ::: "memory");
        }
        __builtin_amdgcn_s_barrier();       // all waves' stage-st loads landed
        __builtin_amdgcn_sched_barrier(0);  // pin ds_reads below the barrier
#pragma unroll
        for (int c = 0; c < 2; ++c) {
            const int kb = 2 * w + c;       // wave-private k-chunks
            short8 a0 = *(const short8*)&lds[b][2 * kb + 0][lane][0];
            short8 a1 = *(const short8*)&lds[b][2 * kb + 1][lane][0];
            short8 p0 = *(const short8*)&lds[b][16 + 2 * kb + 0][lane][0];
            short8 p1 = *(const short8*)&lds[b][16 + 2 * kb + 1][lane][0];
            acc[0][0] = __builtin_amdgcn_mfma_f32_16x16x32_bf16(a0, p0, acc[0][0], 0, 0, 0);
            acc[0][1] = __builtin_amdgcn_mfma_f32_16x16x32_bf16(a0, p1, acc[0][1], 0, 0, 0);
            acc[1][0] = __builtin_amdgcn_mfma_f32_16x16x32_bf16(a1, p0, acc[1][0], 0, 0, 0);
            acc[1][1] = __builtin_amdgcn_mfma_f32_16x16x32_bf16(a1, p1, acc[1][1], 0, 0, 0);
        }
        __builtin_amdgcn_sched_barrier(0);  // pin compute above the drain
        asm volatile("s_waitcnt lgkmcnt(0)" ::: "memory");  // my ds_reads done
        __builtin_amdgcn_s_barrier();       // everyone's reads done -> next STAGE safe
    }

    // Cross-wave K-reduction of partial accumulators through LDS (16 KB).
    float* sc = (float*)&lds[0][0][0][0];
#pragma unroll
    for (int rm = 0; rm < 2; ++rm)
#pragma unroll
        for (int rn = 0; rn < 2; ++rn)
#pragma unroll
            for (int r = 0; r < 4; ++r)
                sc[(((w * 2 + rm) * 2 + rn) * 4 + r) * 64 + lane] = acc[rm][rn][r];
    __syncthreads();

    // Wave w finishes quadrant (rm,rn) = (w>>1, w&1).
    // C/D layout: col=lane&15, row=(lane>>4)*4+r [m89-verified]
    const int rm = w >> 1, rn = w & 1;
    const int jj = j0 + rn * 16 + (lane & 15);
    const int ib = i0 + rm * 16 + ((lane >> 4) << 2);
    const float spv = ws[512 + jj];
    float lsum = 0.f;
    unsigned int lcnt = 0;
#pragma unroll
    for (int r = 0; r < 4; ++r) {
        const float dot = sc[(((0 * 2 + rm) * 2 + rn) * 4 + r) * 64 + lane]
                        + sc[(((1 * 2 + rm) * 2 + rn) * 4 + r) * 64 + lane]
                        + sc[(((2 * 2 + rm) * 2 + rn) * 4 + r) * 64 + lane]
                        + sc[(((3 * 2 + rm) * 2 + rn) * 4 + r) * 64 + lane];
        const int ii = ib + r;
        float d2 = ws[ii] - 2.f * dot + spv;
        d2 = fmaxf(d2, 0.f);
        const float dist = (d2 == 0.f) ? 0.f : sqrtf(d2);
        const float v = (ii != jj) ? fmaxf(ws[1024 + ii] - dist, 0.f) : 0.f;
        lsum += v;
        lcnt += (v > 1e-16f) ? 1u : 0u;
    }
#pragma unroll
    for (int off = 32; off > 0; off >>= 1) {
        lsum += __shfl_down(lsum, off, 64);
        lcnt += __shfl_down(lcnt, off, 64);
    }
    float* rs = sc + 4096;                       // carved block-reduce scratch
    unsigned int* rc = (unsigned int*)(sc + 4100);
    if ((t & 63) == 0) { rs[w] = lsum; rc[w] = lcnt; }
    __syncthreads();
    if (t == 0) {
        atomicAdd(ws + 1536, rs[0] + rs[1] + rs[2] + rs[3]);
        atomicAdd(((unsigned int*)ws) + 1537, rc[0] + rc[1] + rc[2] + rc[3]);
        __threadfence();  // make this block's sums device-visible before ticket
        const unsigned int old = atomicAdd(((unsigned int*)ws) + 1538, 1u);
        if (old == 255u) {  // last block: all 256 blocks' atomics are visible
            const float s = atomicAdd(ws + 1536, 0.f);          // coherent read
            const unsigned int c = atomicAdd(((unsigned int*)ws) + 1537, 0u);
            out[0] = (float)((double)s / ((double)c + 1e-16));
        }
    }
}

// ---------------- finalize (fallback path only) ----------------
__global__ void taw_finalize_kernel(const float* __restrict__ ws,
                                    float* __restrict__ out) {
    const double s = (double)ws[1536];
    const double c = (double)(((const unsigned int*)ws)[1537]);
    out[0] = (float)(s / (c + 1e-16));
}

// ---------------- fallback single-pass fp32 GEMM (Round-0/1 proven path) ----------------
__global__ __launch_bounds__(256) void taw_gemm_loss_kernel(
        const float* __restrict__ A, const float* __restrict__ P,
        float* __restrict__ ws) {
    __shared__ float as[32][34];
    __shared__ float bs[32][34];
    const int tx = threadIdx.x;
    const int ty = threadIdx.y;
    const int t = ty * 16 + tx;
    const int i0 = blockIdx.y * 32;
    const int j0 = blockIdx.x * 32;
    const int sr = t >> 3;
    const int sk = (t & 7) * 4;
    const float* aptr = A + (size_t)(i0 + sr) * PD + sk;
    const float* pptr = P + (size_t)(j0 + sr) * PD + sk;
    float c00 = 0.f, c01 = 0.f, c10 = 0.f, c11 = 0.f;
    for (int k0 = 0; k0 < PD; k0 += 32) {
        float4 av = *(const float4*)(aptr + k0);
        float4 pv = *(const float4*)(pptr + k0);
        __syncthreads();
        as[sk + 0][sr] = av.x; as[sk + 1][sr] = av.y;
        as[sk + 2][sr] = av.z; as[sk + 3][sr] = av.w;
        bs[sk + 0][sr] = pv.x; bs[sk + 1][sr] = pv.y;
        bs[sk + 2][sr] = pv.z; bs[sk + 3][sr] = pv.w;
        __syncthreads();
#pragma unroll
        for (int kk = 0; kk < 32; ++kk) {
            const float2 a2 = *(const float2*)&as[kk][2 * ty];
            const float2 b2 = *(const float2*)&bs[kk][2 * tx];
            c00 = fmaf(a2.x, b2.x, c00);
            c01 = fmaf(a2.x, b2.y, c01);
            c10 = fmaf(a2.y, b2.x, c10);
            c11 = fmaf(a2.y, b2.y, c11);
        }
    }
    const float* sq_a = ws;
    const float* sq_p = ws + 512;
    const float* ddg  = ws + 1024;
    const int i = i0 + 2 * ty;
    const int j = j0 + 2 * tx;
    float cvals[2][2] = {{c00, c01}, {c10, c11}};
    float lsum = 0.f;
    unsigned int lcnt = 0;
#pragma unroll
    for (int dr = 0; dr < 2; ++dr)
#pragma unroll
        for (int dc = 0; dc < 2; ++dc) {
            const int ii = i + dr, jj = j + dc;
            float d2 = sq_a[ii] - 2.f * cvals[dr][dc] + sq_p[jj];
            d2 = fmaxf(d2, 0.f);
            const float dist = (d2 == 0.f) ? 0.f : sqrtf(d2);
            const float v = (ii != jj) ? fmaxf(ddg[ii] - dist, 0.f) : 0.f;
            lsum += v;
            lcnt += (v > 1e-16f) ? 1u : 0u;
        }
#pragma unroll
    for (int off = 32; off > 0; off >>= 1) {
        lsum += __shfl_down(lsum, off, 64);
        lcnt += __shfl_down(lcnt, off, 64);
    }
    __shared__ float rsum[4];
    __shared__ unsigned int rcnt[4];
    if ((t & 63) == 0) { rsum[t >> 6] = lsum; rcnt[t >> 6] = lcnt; }
    __syncthreads();
    if (t == 0) {
        atomicAdd(ws + 1536, rsum[0] + rsum[1] + rsum[2] + rsum[3]);
        atomicAdd(((unsigned int*)ws) + 1537, rcnt[0] + rcnt[1] + rcnt[2] + rcnt[3]);
    }
}

extern "C" void kernel_launch(void* const* d_in, const int* in_sizes, int n_in,
                              void* d_out, int out_size, void* d_ws, size_t ws_size,
                              hipStream_t stream) {
    (void)in_sizes; (void)n_in; (void)out_size;
    const float* a = (const float*)d_in[0];
    const float* p = (const float*)d_in[1];
    float* out = (float*)d_out;
    float* ws = (float*)d_ws;

    const int use_mfma = (ws_size >= WS_NEED_MAIN) ? 1 : 0;
    taw_prep_kernel<<<PN, 256, 0, stream>>>(a, p, ws, use_mfma);
    if (use_mfma) {
        taw_fused_kernel<<<256, 256, 0, stream>>>(ws, out);
    } else {
        taw_gemm_loss_kernel<<<dim3(16, 16), dim3(16, 16), 0, stream>>>(a, p, ws);
        taw_finalize_kernel<<<1, 1, 0, stream>>>(ws, out);
    }
}